// Round 1
// 2663.823 us; speedup vs baseline: 1.1224x; 1.1224x over previous
//
#include <hip/hip_runtime.h>
#include <math.h>

#define NN 100000
#define NE 640000
#define DD 128
#define HH 256
#define NL 3
#define QDIM 768
#define TM 64

#define A1P 392   // f16 pitch for [64][384] staged features (+8 pad)
#define A2P 264   // f16 pitch for [64][256] hidden

typedef _Float16 h16x8 __attribute__((ext_vector_type(8)));
typedef float f32x4 __attribute__((ext_vector_type(4)));

#define MFMA16(A, B, C) __builtin_amdgcn_mfma_f32_16x16x32_f16(A, B, C, 0, 0, 0)

__device__ __forceinline__ unsigned short f2h_bits(float f) {
    _Float16 h = (_Float16)f;                 // v_cvt_f16_f32, RTN
    return __builtin_bit_cast(unsigned short, h);
}

// ---------------- q = question_embedding @ qW + qb (fp32, tiny) ----------------
__global__ void q_kernel(const float* __restrict__ qe, const float* __restrict__ qW,
                         const float* __restrict__ qb, float* __restrict__ q) {
    int d = threadIdx.x;  // 128 threads
    float acc = qb[d];
    for (int k = 0; k < QDIM; ++k) acc = fmaf(qe[k], qW[k * DD + d], acc);
    q[d] = acc;
}

// qc[l][h] = eb1[l][h] + sum_d q[d] * eW1[l][3D + d][h]   (fp32-exact q segment)
__global__ void qc_kernel(const float* __restrict__ q, const float* __restrict__ eW1,
                          const float* __restrict__ eb1, float* __restrict__ qc) {
    int l = blockIdx.x;
    int h = threadIdx.x;  // 256 threads
    const float* W = eW1 + ((size_t)l * 4 * DD + 3 * DD) * HH;
    __shared__ float sq[DD];
    if (h < DD) sq[h] = q[h];
    __syncthreads();
    float acc = eb1[l * HH + h];
    for (int d = 0; d < DD; ++d) acc = fmaf(sq[d], W[d * HH + h], acc);
    qc[l * HH + h] = acc;
}

// ---- pack fp32 weight [l][K x Ncols] -> f16 MFMA B-fragments, hi plane + lo plane ----
__global__ void pack_kernel(const float* __restrict__ W, unsigned short* __restrict__ out,
                            int K, int Ncols, int lstride, size_t plane /*shorts*/) {
    int nct = Ncols >> 4;
    int bx = blockIdx.x;
    int l = blockIdx.y;
    int lane = threadIdx.x;
    const float* Wl = W + (size_t)l * lstride;
    int kt = bx / nct, ct = bx - kt * nct;
    int r = kt * 32 + (lane >> 4) * 8;
    int c = ct * 16 + (lane & 15);
    unsigned vh[4], vl[4];
#pragma unroll
    for (int p = 0; p < 4; ++p) {
        float x0 = Wl[(size_t)(r + 2 * p) * Ncols + c];
        float x1 = Wl[(size_t)(r + 2 * p + 1) * Ncols + c];
        _Float16 h0 = (_Float16)x0, h1 = (_Float16)x1;
        _Float16 l0 = (_Float16)(x0 - (float)h0), l1 = (_Float16)(x1 - (float)h1);
        vh[p] = (unsigned)__builtin_bit_cast(unsigned short, h0) |
                ((unsigned)__builtin_bit_cast(unsigned short, h1) << 16);
        vl[p] = (unsigned)__builtin_bit_cast(unsigned short, l0) |
                ((unsigned)__builtin_bit_cast(unsigned short, l1) << 16);
    }
    size_t off = (size_t)l * K * Ncols + ((size_t)bx * 64 + lane) * 8;
    *(uint4*)(out + off) = make_uint4(vh[0], vh[1], vh[2], vh[3]);
    *(uint4*)(out + plane + off) = make_uint4(vl[0], vl[1], vl[2], vl[3]);
}

// ---------------- CSR build: cnt -> scan -> fill ----------------
__global__ void deg_kernel(const int* __restrict__ eidx, int* __restrict__ cnt) {
    int i = blockIdx.x * 256 + threadIdx.x;
    if (i < 2 * NE) atomicAdd(&cnt[eidx[i]], 1);
}

#define SCAN_T 1024
__global__ void scan_kernel(const int* __restrict__ cnt, int* __restrict__ offsets,
                            int* __restrict__ cursor) {
    __shared__ int s[SCAN_T];
    int t = threadIdx.x;
    const int chunk = (NN + SCAN_T - 1) / SCAN_T;  // 98
    int lo = t * chunk, hi = lo + chunk; if (hi > NN) hi = NN;
    int sum = 0;
    for (int i = lo; i < hi; ++i) sum += cnt[i];
    s[t] = sum;
    __syncthreads();
    for (int off = 1; off < SCAN_T; off <<= 1) {
        int v = (t >= off) ? s[t - off] : 0;
        __syncthreads();
        s[t] += v;
        __syncthreads();
    }
    int run = (t == 0) ? 0 : s[t - 1];
    for (int i = lo; i < hi; ++i) {
        int c = cnt[i];
        offsets[i] = run;
        cursor[i] = run;
        run += c;
    }
    if (t == SCAN_T - 1) offsets[NN] = run;
}

__global__ void fill_kernel(const int* __restrict__ eidx, int* __restrict__ cursor,
                            int* __restrict__ inc) {
    int i = blockIdx.x * 256 + threadIdx.x;
    if (i < 2 * NE) {
        int e = (i < NE) ? i : i - NE;
        int pos = atomicAdd(&cursor[eidx[i]], 1);
        inc[pos] = e;
    }
}

// ---------------- fused edge MLP (f16 MFMA, split-B), TM=64, aliased LDS ----------------
__global__ __launch_bounds__(256, 3) void edge_kernel(
    const float* __restrict__ node_h, float* __restrict__ edge_h,
    const int* __restrict__ eidx,
    const unsigned short* __restrict__ W1hi, const unsigned short* __restrict__ W1lo,
    const float* __restrict__ qc,            // [256] bias incl. q-segment
    const unsigned short* __restrict__ W2hi, const unsigned short* __restrict__ W2lo,
    const float* __restrict__ b2)            // [128]
{
    // sA1 [64][A1P] (50176 B) aliased with sA2 [64][A2P] (33792 B)
    __shared__ unsigned short sA[TM * A1P];
    unsigned short* sA1 = sA;
    unsigned short* sA2 = sA;

    const int tid = threadIdx.x;
    const int e0 = blockIdx.x * TM;

    const int row = tid >> 2, t4 = tid & 3;   // 4 threads per row, 64 rows
    const int srcn = eidx[e0 + row];
    const int dstn = eidx[NE + e0 + row];

    // ---- stage gathered features -> sA1 (f16, row-major, pitch A1P) ----
    {
        const float* b0 = node_h + (size_t)srcn * DD;
        const float* b1 = node_h + (size_t)dstn * DD;
        const float* b2p = edge_h + (size_t)(e0 + row) * DD;
#pragma unroll
        for (int i = 0; i < 24; ++i) {
            int seg = i >> 3;                       // uniform in t4
            int k = (t4 + 4 * i) * 4;               // 0..380
            int klocal = k - seg * DD;
            const float* g = (seg == 0) ? b0 : (seg == 1) ? b1 : b2p;
            float4 v = *(const float4*)(g + klocal);
            uint2 p;
            p.x = (unsigned)f2h_bits(v.x) | ((unsigned)f2h_bits(v.y) << 16);
            p.y = (unsigned)f2h_bits(v.z) | ((unsigned)f2h_bits(v.w) << 16);
            *(uint2*)&sA1[row * A1P + k] = p;
        }
    }

    const int lane = tid & 63;
    const int w = tid >> 6;           // wave id: cols w*64.. (GEMM1), w*32.. (GEMM2)
    const int lrow = lane & 15;
    const int q4 = lane >> 4;

    // ---- GEMM1: [64x384] @ [384x256] -> acc[4][4] ----
    f32x4 acc[4][4];
#pragma unroll
    for (int ct = 0; ct < 4; ++ct) {
        float iv = qc[w * 64 + ct * 16 + lrow];
        f32x4 c = {iv, iv, iv, iv};
#pragma unroll
        for (int rt = 0; rt < 4; ++rt) acc[rt][ct] = c;
    }
    __syncthreads();

    const h16x8* W1h = (const h16x8*)W1hi;
    const h16x8* W1l = (const h16x8*)W1lo;
    for (int kt = 0; kt < 12; ++kt) {
        h16x8 a[4];
#pragma unroll
        for (int rt = 0; rt < 4; ++rt)
            a[rt] = *(const h16x8*)&sA1[(lrow + 16 * rt) * A1P + kt * 32 + q4 * 8];
#pragma unroll
        for (int ct = 0; ct < 4; ++ct) {
            h16x8 bh = W1h[(kt * 16 + w * 4 + ct) * 64 + lane];
            h16x8 bl = W1l[(kt * 16 + w * 4 + ct) * 64 + lane];
#pragma unroll
            for (int rt = 0; rt < 4; ++rt) {
                acc[rt][ct] = MFMA16(a[rt], bh, acc[rt][ct]);
                acc[rt][ct] = MFMA16(a[rt], bl, acc[rt][ct]);
            }
        }
    }

    __syncthreads();   // all sA1 reads done before aliased sA2 writes

    // ---- relu -> f16 hidden in sA2 (aliased over sA1) ----
#pragma unroll
    for (int rt = 0; rt < 4; ++rt)
#pragma unroll
        for (int ct = 0; ct < 4; ++ct)
#pragma unroll
            for (int j = 0; j < 4; ++j) {
                int hr = rt * 16 + q4 * 4 + j;
                int hc = w * 64 + ct * 16 + lrow;
                sA2[hr * A2P + hc] = f2h_bits(fmaxf(acc[rt][ct][j], 0.0f));
            }
    __syncthreads();

    // ---- GEMM2: [64x256] @ [256x128] -> acc2[4][2] ----
    f32x4 acc2[4][2];
#pragma unroll
    for (int ct = 0; ct < 2; ++ct) {
        float iv = b2[w * 32 + ct * 16 + lrow];
        f32x4 c = {iv, iv, iv, iv};
#pragma unroll
        for (int rt = 0; rt < 4; ++rt) acc2[rt][ct] = c;
    }
    const h16x8* W2h = (const h16x8*)W2hi;
    const h16x8* W2l = (const h16x8*)W2lo;
    for (int kt = 0; kt < 8; ++kt) {
        h16x8 a[4];
#pragma unroll
        for (int rt = 0; rt < 4; ++rt)
            a[rt] = *(const h16x8*)&sA2[(lrow + 16 * rt) * A2P + kt * 32 + q4 * 8];
#pragma unroll
        for (int ct = 0; ct < 2; ++ct) {
            h16x8 bh = W2h[(kt * 8 + w * 2 + ct) * 64 + lane];
            h16x8 bl = W2l[(kt * 8 + w * 2 + ct) * 64 + lane];
#pragma unroll
            for (int rt = 0; rt < 4; ++rt) {
                acc2[rt][ct] = MFMA16(a[rt], bh, acc2[rt][ct]);
                acc2[rt][ct] = MFMA16(a[rt], bl, acc2[rt][ct]);
            }
        }
    }

    // ---- epilogue: edge_h in place (fp32) ----
#pragma unroll
    for (int rt = 0; rt < 4; ++rt)
#pragma unroll
        for (int j = 0; j < 4; ++j) {
            int e = e0 + rt * 16 + q4 * 4 + j;
#pragma unroll
            for (int ct = 0; ct < 2; ++ct) {
                int c = w * 32 + ct * 16 + lrow;
                edge_h[(size_t)e * DD + c] = acc2[rt][ct][j];
            }
        }
}

// ---------------- fused node MLP (f16 MFMA, split-B), TM=64, aliased LDS ----
__global__ __launch_bounds__(256, 3) void node_kernel(
    float* __restrict__ node_h, const float* __restrict__ edge_h,
    const int* __restrict__ offsets, const int* __restrict__ inc,
    const unsigned short* __restrict__ W1hi, const unsigned short* __restrict__ W1lo,
    const float* __restrict__ b1,            // [256]
    const unsigned short* __restrict__ W2hi, const unsigned short* __restrict__ W2lo,
    const float* __restrict__ b2)            // [128]
{
    // sA1 [64][A2P] aliased with sA2 [64][A2P] (33792 B)
    __shared__ unsigned short sA[TM * A2P];
    unsigned short* sA1 = sA;
    unsigned short* sA2 = sA;

    const int tid = threadIdx.x;
    const int n0 = blockIdx.x * TM;

    const int row = tid >> 2, t4 = tid & 3;   // 4 threads per row, 64 rows
    const int n = n0 + row;
    const bool vrow = (n < NN);               // NN % 64 != 0: last block partial

    // ---- stage node_h -> sA1 cols [0,128) ----
    if (vrow) {
        const float* g0 = node_h + (size_t)n * DD;
#pragma unroll
        for (int i = 0; i < 8; ++i) {
            int k = (t4 + 4 * i) * 4;               // 0..124
            float4 v = *(const float4*)(g0 + k);
            uint2 p;
            p.x = (unsigned)f2h_bits(v.x) | ((unsigned)f2h_bits(v.y) << 16);
            p.y = (unsigned)f2h_bits(v.z) | ((unsigned)f2h_bits(v.w) << 16);
            *(uint2*)&sA1[row * A2P + k] = p;
        }
    } else {
        uint2 z; z.x = 0; z.y = 0;
#pragma unroll
        for (int i = 0; i < 8; ++i)
            *(uint2*)&sA1[row * A2P + (t4 + 4 * i) * 4] = z;
    }

    // ---- pull-aggregate incident edge rows -> fp32 regs -> sA1 cols [128,256) ----
    {
        int k0 = 0, k1 = 0;
        if (vrow) { k0 = offsets[n]; k1 = offsets[n + 1]; }
        float a[32];
#pragma unroll
        for (int j = 0; j < 32; ++j) a[j] = 0.0f;
        for (int k = k0; k < k1; ++k) {
            int e = inc[k];
            const float* er = edge_h + (size_t)e * DD;
#pragma unroll
            for (int j = 0; j < 8; ++j) {
                float4 v = *(const float4*)(er + j * 16 + t4 * 4);
                a[j * 4 + 0] += v.x;
                a[j * 4 + 1] += v.y;
                a[j * 4 + 2] += v.z;
                a[j * 4 + 3] += v.w;
            }
        }
#pragma unroll
        for (int j = 0; j < 8; ++j) {
            int c = 128 + j * 16 + t4 * 4;
            uint2 p;
            p.x = (unsigned)f2h_bits(a[j * 4 + 0]) | ((unsigned)f2h_bits(a[j * 4 + 1]) << 16);
            p.y = (unsigned)f2h_bits(a[j * 4 + 2]) | ((unsigned)f2h_bits(a[j * 4 + 3]) << 16);
            *(uint2*)&sA1[row * A2P + c] = p;
        }
    }

    const int lane = tid & 63;
    const int w = tid >> 6;
    const int lrow = lane & 15;
    const int q4 = lane >> 4;

    // ---- GEMM1: [64x256] @ [256x256] -> acc[4][4] ----
    f32x4 acc[4][4];
#pragma unroll
    for (int ct = 0; ct < 4; ++ct) {
        float iv = b1[w * 64 + ct * 16 + lrow];
        f32x4 c = {iv, iv, iv, iv};
#pragma unroll
        for (int rt = 0; rt < 4; ++rt) acc[rt][ct] = c;
    }
    __syncthreads();

    const h16x8* W1h = (const h16x8*)W1hi;
    const h16x8* W1l = (const h16x8*)W1lo;
    for (int kt = 0; kt < 8; ++kt) {
        h16x8 a[4];
#pragma unroll
        for (int rt = 0; rt < 4; ++rt)
            a[rt] = *(const h16x8*)&sA1[(lrow + 16 * rt) * A2P + kt * 32 + q4 * 8];
#pragma unroll
        for (int ct = 0; ct < 4; ++ct) {
            h16x8 bh = W1h[(kt * 16 + w * 4 + ct) * 64 + lane];
            h16x8 bl = W1l[(kt * 16 + w * 4 + ct) * 64 + lane];
#pragma unroll
            for (int rt = 0; rt < 4; ++rt) {
                acc[rt][ct] = MFMA16(a[rt], bh, acc[rt][ct]);
                acc[rt][ct] = MFMA16(a[rt], bl, acc[rt][ct]);
            }
        }
    }

    __syncthreads();   // all sA1 reads done before aliased sA2 writes

#pragma unroll
    for (int rt = 0; rt < 4; ++rt)
#pragma unroll
        for (int ct = 0; ct < 4; ++ct)
#pragma unroll
            for (int j = 0; j < 4; ++j) {
                int hr = rt * 16 + q4 * 4 + j;
                int hc = w * 64 + ct * 16 + lrow;
                sA2[hr * A2P + hc] = f2h_bits(fmaxf(acc[rt][ct][j], 0.0f));
            }
    __syncthreads();

    // ---- GEMM2: [64x256] @ [256x128] -> acc2[4][2] ----
    f32x4 acc2[4][2];
#pragma unroll
    for (int ct = 0; ct < 2; ++ct) {
        float iv = b2[w * 32 + ct * 16 + lrow];
        f32x4 c = {iv, iv, iv, iv};
#pragma unroll
        for (int rt = 0; rt < 4; ++rt) acc2[rt][ct] = c;
    }
    const h16x8* W2h = (const h16x8*)W2hi;
    const h16x8* W2l = (const h16x8*)W2lo;
    for (int kt = 0; kt < 8; ++kt) {
        h16x8 a[4];
#pragma unroll
        for (int rt = 0; rt < 4; ++rt)
            a[rt] = *(const h16x8*)&sA2[(lrow + 16 * rt) * A2P + kt * 32 + q4 * 8];
#pragma unroll
        for (int ct = 0; ct < 2; ++ct) {
            h16x8 bh = W2h[(kt * 8 + w * 2 + ct) * 64 + lane];
            h16x8 bl = W2l[(kt * 8 + w * 2 + ct) * 64 + lane];
#pragma unroll
            for (int rt = 0; rt < 4; ++rt) {
                acc2[rt][ct] = MFMA16(a[rt], bh, acc2[rt][ct]);
                acc2[rt][ct] = MFMA16(a[rt], bl, acc2[rt][ct]);
            }
        }
    }

#pragma unroll
    for (int rt = 0; rt < 4; ++rt)
#pragma unroll
        for (int j = 0; j < 4; ++j) {
            int rr = rt * 16 + q4 * 4 + j;
            if (n0 + rr < NN) {
#pragma unroll
                for (int ct = 0; ct < 2; ++ct) {
                    int c = w * 32 + ct * 16 + lrow;
                    node_h[(size_t)(n0 + rr) * DD + c] = acc2[rt][ct][j];
                }
            }
        }
}

// ---------------- sigmoid(h @ w + b) ----------------
__global__ void score_kernel(const float* __restrict__ hmat, const float* __restrict__ w,
                             const float* __restrict__ b, float* __restrict__ out) {
    int wid = threadIdx.x >> 6;        // 4 waves per block, one row each
    int lane = threadIdx.x & 63;
    int row = blockIdx.x * 4 + wid;
    float2 v  = *(const float2*)(hmat + (size_t)row * DD + lane * 2);
    float2 wv = *(const float2*)(w + lane * 2);
    float s = v.x * wv.x + v.y * wv.y;
#pragma unroll
    for (int off = 32; off; off >>= 1) s += __shfl_down(s, off);
    if (lane == 0) out[row] = 1.0f / (1.0f + expf(-(s + b[0])));
}

extern "C" void kernel_launch(void* const* d_in, const int* in_sizes, int n_in,
                              void* d_out, int out_size, void* d_ws, size_t ws_size,
                              hipStream_t stream) {
    float* node_h = (float*)d_in[0];            // mutated in place (restored each launch)
    float* edge_h = (float*)d_in[1];            // mutated in place
    const float* qe   = (const float*)d_in[2];
    const int*   eidx = (const int*)d_in[3];
    // d_in[4] edge_type: unused
    const float* qW  = (const float*)d_in[5];
    const float* qb  = (const float*)d_in[6];
    const float* eW1 = (const float*)d_in[7];
    const float* eb1 = (const float*)d_in[8];
    const float* eW2 = (const float*)d_in[9];
    const float* eb2 = (const float*)d_in[10];
    const float* nW1 = (const float*)d_in[11];
    const float* nb1 = (const float*)d_in[12];
    const float* nW2 = (const float*)d_in[13];
    const float* nb2 = (const float*)d_in[14];
    const float* esW = (const float*)d_in[15];
    const float* esb = (const float*)d_in[16];
    const float* nsW = (const float*)d_in[17];
    const float* nsb = (const float*)d_in[18];

    float* ws  = (float*)d_ws;
    float* q   = ws;            // 128 floats
    float* qc  = ws + 256;      // 3*256 floats
    int* cnt     = (int*)(ws + 1024);   // NN
    int* cursor  = cnt + NN;            // NN
    int* offsets = cursor + NN;         // NN+1
    int* inc     = offsets + NN + 1;    // 2*NE   (total ~6.3 MB)

    // f16 weight packs (hi+lo planes) live in d_out (dead until score writes).
    unsigned short* packs = (unsigned short*)d_out;
    const size_t pe1 = (size_t)NL * 384 * 256;
    const size_t pe2 = (size_t)NL * 256 * 128;
    const size_t pn1 = (size_t)NL * 256 * 256;
    const size_t pn2 = (size_t)NL * 256 * 128;
    unsigned short* eW1p = packs;
    unsigned short* eW2p = eW1p + 2 * pe1;
    unsigned short* nW1p = eW2p + 2 * pe2;
    unsigned short* nW2p = nW1p + 2 * pn1;

    q_kernel<<<1, DD, 0, stream>>>(qe, qW, qb, q);
    qc_kernel<<<NL, HH, 0, stream>>>(q, eW1, eb1, qc);
    pack_kernel<<<dim3(12 * 16, NL), 64, 0, stream>>>(eW1, eW1p, 384, 256, 4 * DD * HH, pe1);
    pack_kernel<<<dim3(8 * 8, NL), 64, 0, stream>>>(eW2, eW2p, 256, 128, HH * DD, pe2);
    pack_kernel<<<dim3(8 * 16, NL), 64, 0, stream>>>(nW1, nW1p, 256, 256, 2 * DD * HH, pn1);
    pack_kernel<<<dim3(8 * 8, NL), 64, 0, stream>>>(nW2, nW2p, 256, 128, HH * DD, pn2);

    // ---- CSR incidence build (once; edge_index is layer-invariant) ----
    hipMemsetAsync(cnt, 0, NN * sizeof(int), stream);
    deg_kernel<<<(2 * NE + 255) / 256, 256, 0, stream>>>(eidx, cnt);
    scan_kernel<<<1, SCAN_T, 0, stream>>>(cnt, offsets, cursor);
    fill_kernel<<<(2 * NE + 255) / 256, 256, 0, stream>>>(eidx, cursor, inc);

    for (int l = 0; l < NL; ++l) {
        edge_kernel<<<NE / TM, 256, 0, stream>>>(
            node_h, edge_h, eidx,
            eW1p + (size_t)l * 384 * 256, eW1p + pe1 + (size_t)l * 384 * 256,
            qc + l * HH,
            eW2p + (size_t)l * 256 * 128, eW2p + pe2 + (size_t)l * 256 * 128,
            eb2 + l * DD);
        node_kernel<<<(NN + TM - 1) / TM, 256, 0, stream>>>(
            node_h, edge_h, offsets, inc,
            nW1p + (size_t)l * 256 * 256, nW1p + pn1 + (size_t)l * 256 * 256,
            nb1 + l * HH,
            nW2p + (size_t)l * 256 * 128, nW2p + pn2 + (size_t)l * 256 * 128,
            nb2 + l * DD);
    }

    score_kernel<<<NN / 4, 256, 0, stream>>>(node_h, nsW, nsb, (float*)d_out);
    score_kernel<<<NE / 4, 256, 0, stream>>>(edge_h, esW, esb, (float*)d_out + NN);
}

// Round 3
// 2302.292 us; speedup vs baseline: 1.2986x; 1.1570x over previous
//
#include <hip/hip_runtime.h>
#include <math.h>

#define NN 100000
#define NE 640000
#define DD 128
#define HH 256
#define NL 3
#define QDIM 768
#define TM 64

#define A1P 392   // f16 pitch for [64][384] staged features (+8 pad)  (784 B/row, 16B-aligned)
#define A2P 264   // f16 pitch for [64][256] hidden                    (528 B/row, 16B-aligned)
#define OP  136   // f16 pitch for [64][128] output stage              (272 B/row, 16B-aligned)

typedef _Float16 h16x8 __attribute__((ext_vector_type(8)));
typedef float f32x4 __attribute__((ext_vector_type(4)));

#define MFMA16(A, B, C) __builtin_amdgcn_mfma_f32_16x16x32_f16(A, B, C, 0, 0, 0)

__device__ __forceinline__ unsigned short f2h_bits(float f) {
    _Float16 h = (_Float16)f;                 // v_cvt_f16_f32, RTN
    return __builtin_bit_cast(unsigned short, h);
}
__device__ __forceinline__ unsigned pk2(float a, float b) {
    return (unsigned)f2h_bits(a) | ((unsigned)f2h_bits(b) << 16);
}
__device__ __forceinline__ float h2f(unsigned short u) {
    return (float)__builtin_bit_cast(_Float16, u);
}

// ---------------- q = question_embedding @ qW + qb (fp32, tiny) ----------------
__global__ void q_kernel(const float* __restrict__ qe, const float* __restrict__ qW,
                         const float* __restrict__ qb, float* __restrict__ q) {
    int d = threadIdx.x;  // 128 threads
    float acc = qb[d];
    for (int k = 0; k < QDIM; ++k) acc = fmaf(qe[k], qW[k * DD + d], acc);
    q[d] = acc;
}

// qc[l][h] = eb1[l][h] + sum_d q[d] * eW1[l][3D + d][h]   (fp32-exact q segment)
__global__ void qc_kernel(const float* __restrict__ q, const float* __restrict__ eW1,
                          const float* __restrict__ eb1, float* __restrict__ qc) {
    int l = blockIdx.x;
    int h = threadIdx.x;  // 256 threads
    const float* W = eW1 + ((size_t)l * 4 * DD + 3 * DD) * HH;
    __shared__ float sq[DD];
    if (h < DD) sq[h] = q[h];
    __syncthreads();
    float acc = eb1[l * HH + h];
    for (int d = 0; d < DD; ++d) acc = fmaf(sq[d], W[d * HH + h], acc);
    qc[l * HH + h] = acc;
}

// ---- pack fp32 weight [l][K x Ncols] -> f16 MFMA B-fragments, hi plane + lo plane ----
__global__ void pack_kernel(const float* __restrict__ W, unsigned short* __restrict__ out,
                            int K, int Ncols, int lstride, size_t plane /*shorts*/) {
    int nct = Ncols >> 4;
    int bx = blockIdx.x;
    int l = blockIdx.y;
    int lane = threadIdx.x;
    const float* Wl = W + (size_t)l * lstride;
    int kt = bx / nct, ct = bx - kt * nct;
    int r = kt * 32 + (lane >> 4) * 8;
    int c = ct * 16 + (lane & 15);
    unsigned vh[4], vl[4];
#pragma unroll
    for (int p = 0; p < 4; ++p) {
        float x0 = Wl[(size_t)(r + 2 * p) * Ncols + c];
        float x1 = Wl[(size_t)(r + 2 * p + 1) * Ncols + c];
        _Float16 h0 = (_Float16)x0, h1 = (_Float16)x1;
        _Float16 l0 = (_Float16)(x0 - (float)h0), l1 = (_Float16)(x1 - (float)h1);
        vh[p] = (unsigned)__builtin_bit_cast(unsigned short, h0) |
                ((unsigned)__builtin_bit_cast(unsigned short, h1) << 16);
        vl[p] = (unsigned)__builtin_bit_cast(unsigned short, l0) |
                ((unsigned)__builtin_bit_cast(unsigned short, l1) << 16);
    }
    size_t off = (size_t)l * K * Ncols + ((size_t)bx * 64 + lane) * 8;
    *(uint4*)(out + off) = make_uint4(vh[0], vh[1], vh[2], vh[3]);
    *(uint4*)(out + plane + off) = make_uint4(vl[0], vl[1], vl[2], vl[3]);
}

// ---------------- CSR build: cnt -> scan -> fill ----------------
__global__ void deg_kernel(const int* __restrict__ eidx, int* __restrict__ cnt) {
    int i = blockIdx.x * 256 + threadIdx.x;
    if (i < 2 * NE) atomicAdd(&cnt[eidx[i]], 1);
}

#define SCAN_T 1024
__global__ void scan_kernel(const int* __restrict__ cnt, int* __restrict__ offsets,
                            int* __restrict__ cursor) {
    __shared__ int s[SCAN_T];
    int t = threadIdx.x;
    const int chunk = (NN + SCAN_T - 1) / SCAN_T;  // 98
    int lo = t * chunk, hi = lo + chunk; if (hi > NN) hi = NN;
    int sum = 0;
    for (int i = lo; i < hi; ++i) sum += cnt[i];
    s[t] = sum;
    __syncthreads();
    for (int off = 1; off < SCAN_T; off <<= 1) {
        int v = (t >= off) ? s[t - off] : 0;
        __syncthreads();
        s[t] += v;
        __syncthreads();
    }
    int run = (t == 0) ? 0 : s[t - 1];
    for (int i = lo; i < hi; ++i) {
        int c = cnt[i];
        offsets[i] = run;
        cursor[i] = run;
        run += c;
    }
    if (t == SCAN_T - 1) offsets[NN] = run;
}

__global__ void fill_kernel(const int* __restrict__ eidx, int* __restrict__ cursor,
                            int* __restrict__ inc) {
    int i = blockIdx.x * 256 + threadIdx.x;
    if (i < 2 * NE) {
        int e = (i < NE) ? i : i - NE;
        int pos = atomicAdd(&cursor[eidx[i]], 1);
        inc[pos] = e;
    }
}

// ---------------- fused edge MLP (f16 MFMA, split-B), TM=64, f16 activations ----------
// Activations stored f16 in-place: row n occupies first 256B of its 512B fp32 slot
// (stride 256 halfs). IN16=false (layer 0) reads the original fp32 embeddings.
template <bool IN16>
__global__ __launch_bounds__(256, 3) void edge_kernel(
    const void* node_in, const void* edge_in,
    unsigned short* edge_out,                 // f16 rows, stride 256 halfs
    const int* __restrict__ eidx,
    const unsigned short* __restrict__ W1hi, const unsigned short* __restrict__ W1lo,
    const float* __restrict__ qc,            // [256] bias incl. q-segment
    const unsigned short* __restrict__ W2hi, const unsigned short* __restrict__ W2lo,
    const float* __restrict__ b2)            // [128]
{
    // sA1 [64][A1P] (50176 B) aliased with sA2 [64][A2P] and sOut [64][OP]
    __shared__ unsigned short sA[TM * A1P];
    unsigned short* sA1 = sA;
    unsigned short* sA2 = sA;
    unsigned short* sOut = sA;

    const int tid = threadIdx.x;
    const int e0 = blockIdx.x * TM;

    const int row = tid >> 2, t4 = tid & 3;   // 4 threads per row, 64 rows
    const int srcn = eidx[e0 + row];
    const int dstn = eidx[NE + e0 + row];

    // ---- stage gathered features -> sA1 (f16, row-major, pitch A1P) ----
    if (IN16) {
        const unsigned short* b0 = (const unsigned short*)node_in + (size_t)srcn * 256;
        const unsigned short* b1 = (const unsigned short*)node_in + (size_t)dstn * 256;
        const unsigned short* bp = (const unsigned short*)edge_in + (size_t)(e0 + row) * 256;
#pragma unroll
        for (int i = 0; i < 12; ++i) {
            int seg = i >> 2, j = i & 3;
            int c = (t4 + 4 * j) * 8;               // half offset within segment, 0..120
            const unsigned short* g = (seg == 0) ? b0 : (seg == 1) ? b1 : bp;
            *(uint4*)&sA1[row * A1P + seg * 128 + c] = *(const uint4*)(g + c);
        }
    } else {
        const float* b0 = (const float*)node_in + (size_t)srcn * DD;
        const float* b1 = (const float*)node_in + (size_t)dstn * DD;
        const float* bp = (const float*)edge_in + (size_t)(e0 + row) * DD;
#pragma unroll
        for (int i = 0; i < 12; ++i) {
            int seg = i >> 2, j = i & 3;
            int c = (t4 + 4 * j) * 8;               // float offset within segment
            const float* g = (seg == 0) ? b0 : (seg == 1) ? b1 : bp;
            float4 v0 = *(const float4*)(g + c);
            float4 v1 = *(const float4*)(g + c + 4);
            uint4 p = make_uint4(pk2(v0.x, v0.y), pk2(v0.z, v0.w),
                                 pk2(v1.x, v1.y), pk2(v1.z, v1.w));
            *(uint4*)&sA1[row * A1P + seg * 128 + c] = p;
        }
    }

    const int lane = tid & 63;
    const int w = tid >> 6;           // wave id: cols w*64.. (GEMM1), w*32.. (GEMM2)
    const int lrow = lane & 15;
    const int q4 = lane >> 4;

    // ---- GEMM1: [64x384] @ [384x256] -> acc[4][4] ----
    f32x4 acc[4][4];
#pragma unroll
    for (int ct = 0; ct < 4; ++ct) {
        float iv = qc[w * 64 + ct * 16 + lrow];
        f32x4 c = {iv, iv, iv, iv};
#pragma unroll
        for (int rt = 0; rt < 4; ++rt) acc[rt][ct] = c;
    }
    __syncthreads();

    const h16x8* W1h = (const h16x8*)W1hi;
    const h16x8* W1l = (const h16x8*)W1lo;
    for (int kt = 0; kt < 12; ++kt) {
        h16x8 a[4];
#pragma unroll
        for (int rt = 0; rt < 4; ++rt)
            a[rt] = *(const h16x8*)&sA1[(lrow + 16 * rt) * A1P + kt * 32 + q4 * 8];
#pragma unroll
        for (int ct = 0; ct < 4; ++ct) {
            h16x8 bh = W1h[(kt * 16 + w * 4 + ct) * 64 + lane];
            h16x8 bl = W1l[(kt * 16 + w * 4 + ct) * 64 + lane];
#pragma unroll
            for (int rt = 0; rt < 4; ++rt) {
                acc[rt][ct] = MFMA16(a[rt], bh, acc[rt][ct]);
                acc[rt][ct] = MFMA16(a[rt], bl, acc[rt][ct]);
            }
        }
    }

    __syncthreads();   // all sA1 reads done before aliased sA2 writes

    // ---- relu -> f16 hidden in sA2 (aliased over sA1) ----
#pragma unroll
    for (int rt = 0; rt < 4; ++rt)
#pragma unroll
        for (int ct = 0; ct < 4; ++ct)
#pragma unroll
            for (int j = 0; j < 4; ++j) {
                int hr = rt * 16 + q4 * 4 + j;
                int hc = w * 64 + ct * 16 + lrow;
                sA2[hr * A2P + hc] = f2h_bits(fmaxf(acc[rt][ct][j], 0.0f));
            }
    __syncthreads();

    // ---- GEMM2: [64x256] @ [256x128] -> acc2[4][2] ----
    f32x4 acc2[4][2];
#pragma unroll
    for (int ct = 0; ct < 2; ++ct) {
        float iv = b2[w * 32 + ct * 16 + lrow];
        f32x4 c = {iv, iv, iv, iv};
#pragma unroll
        for (int rt = 0; rt < 4; ++rt) acc2[rt][ct] = c;
    }
    const h16x8* W2h = (const h16x8*)W2hi;
    const h16x8* W2l = (const h16x8*)W2lo;
    for (int kt = 0; kt < 8; ++kt) {
        h16x8 a[4];
#pragma unroll
        for (int rt = 0; rt < 4; ++rt)
            a[rt] = *(const h16x8*)&sA2[(lrow + 16 * rt) * A2P + kt * 32 + q4 * 8];
#pragma unroll
        for (int ct = 0; ct < 2; ++ct) {
            h16x8 bh = W2h[(kt * 8 + w * 2 + ct) * 64 + lane];
            h16x8 bl = W2l[(kt * 8 + w * 2 + ct) * 64 + lane];
#pragma unroll
            for (int rt = 0; rt < 4; ++rt) {
                acc2[rt][ct] = MFMA16(a[rt], bh, acc2[rt][ct]);
                acc2[rt][ct] = MFMA16(a[rt], bl, acc2[rt][ct]);
            }
        }
    }

    // ---- epilogue: acc2 -> LDS out-stage (f16) -> coalesced 16B global stores ----
    __syncthreads();   // sA2 reads done before aliased sOut writes
#pragma unroll
    for (int rt = 0; rt < 4; ++rt)
#pragma unroll
        for (int j = 0; j < 4; ++j) {
            int rr = rt * 16 + q4 * 4 + j;
#pragma unroll
            for (int ct = 0; ct < 2; ++ct)
                sOut[rr * OP + w * 32 + ct * 16 + lrow] = f2h_bits(acc2[rt][ct][j]);
        }
    __syncthreads();
    {
        unsigned short* er = edge_out + (size_t)(e0 + row) * 256;
#pragma unroll
        for (int j = 0; j < 4; ++j)
            *(uint4*)(er + t4 * 32 + j * 8) = *(const uint4*)&sOut[row * OP + t4 * 32 + j * 8];
    }
}

// ---------------- fused node MLP (f16 MFMA, split-B), TM=64, f16 activations -----
template <bool IN16>
__global__ __launch_bounds__(256, 3) void node_kernel(
    const void* node_in, unsigned short* node_out,     // f16 rows, stride 256 halfs
    const unsigned short* __restrict__ edge16,         // f16 rows, stride 256 halfs
    const int* __restrict__ offsets, const int* __restrict__ inc,
    const unsigned short* __restrict__ W1hi, const unsigned short* __restrict__ W1lo,
    const float* __restrict__ b1,            // [256]
    const unsigned short* __restrict__ W2hi, const unsigned short* __restrict__ W2lo,
    const float* __restrict__ b2)            // [128]
{
    // sA1 [64][A2P] (33792 B) aliased with sA2 and sOut
    __shared__ unsigned short sA[TM * A2P];
    unsigned short* sA1 = sA;
    unsigned short* sA2 = sA;
    unsigned short* sOut = sA;

    const int tid = threadIdx.x;
    const int n0 = blockIdx.x * TM;

    const int row = tid >> 2, t4 = tid & 3;   // 4 threads per row, 64 rows
    const int n = n0 + row;
    const bool vrow = (n < NN);               // NN % 64 != 0: last block partial

    // ---- stage node features -> sA1 cols [0,128) ----
    if (vrow) {
        if (IN16) {
            const unsigned short* g0 = (const unsigned short*)node_in + (size_t)n * 256;
#pragma unroll
            for (int j = 0; j < 4; ++j) {
                int c = t4 * 32 + j * 8;
                *(uint4*)&sA1[row * A2P + c] = *(const uint4*)(g0 + c);
            }
        } else {
            const float* g0 = (const float*)node_in + (size_t)n * DD;
#pragma unroll
            for (int j = 0; j < 4; ++j) {
                int c = t4 * 32 + j * 8;
                float4 v0 = *(const float4*)(g0 + c);
                float4 v1 = *(const float4*)(g0 + c + 4);
                uint4 p = make_uint4(pk2(v0.x, v0.y), pk2(v0.z, v0.w),
                                     pk2(v1.x, v1.y), pk2(v1.z, v1.w));
                *(uint4*)&sA1[row * A2P + c] = p;
            }
        }
    } else {
        uint4 z = make_uint4(0, 0, 0, 0);
#pragma unroll
        for (int j = 0; j < 4; ++j)
            *(uint4*)&sA1[row * A2P + t4 * 32 + j * 8] = z;
    }

    // ---- pull-aggregate incident f16 edge rows -> fp32 regs -> sA1 cols [128,256) ----
    {
        int k0 = 0, k1 = 0;
        if (vrow) { k0 = offsets[n]; k1 = offsets[n + 1]; }
        float a[32];
#pragma unroll
        for (int j = 0; j < 32; ++j) a[j] = 0.0f;
        for (int k = k0; k < k1; ++k) {
            int e = inc[k];
            const unsigned short* er = edge16 + (size_t)e * 256 + t4 * 32;
#pragma unroll
            for (int j = 0; j < 4; ++j) {
                uint4 v = *(const uint4*)(er + j * 8);
                a[j * 8 + 0] += h2f((unsigned short)(v.x & 0xffff));
                a[j * 8 + 1] += h2f((unsigned short)(v.x >> 16));
                a[j * 8 + 2] += h2f((unsigned short)(v.y & 0xffff));
                a[j * 8 + 3] += h2f((unsigned short)(v.y >> 16));
                a[j * 8 + 4] += h2f((unsigned short)(v.z & 0xffff));
                a[j * 8 + 5] += h2f((unsigned short)(v.z >> 16));
                a[j * 8 + 6] += h2f((unsigned short)(v.w & 0xffff));
                a[j * 8 + 7] += h2f((unsigned short)(v.w >> 16));
            }
        }
#pragma unroll
        for (int j = 0; j < 4; ++j) {
            uint4 p = make_uint4(pk2(a[j * 8 + 0], a[j * 8 + 1]), pk2(a[j * 8 + 2], a[j * 8 + 3]),
                                 pk2(a[j * 8 + 4], a[j * 8 + 5]), pk2(a[j * 8 + 6], a[j * 8 + 7]));
            *(uint4*)&sA1[row * A2P + 128 + t4 * 32 + j * 8] = p;
        }
    }

    const int lane = tid & 63;
    const int w = tid >> 6;
    const int lrow = lane & 15;
    const int q4 = lane >> 4;

    // ---- GEMM1: [64x256] @ [256x256] -> acc[4][4] ----
    f32x4 acc[4][4];
#pragma unroll
    for (int ct = 0; ct < 4; ++ct) {
        float iv = b1[w * 64 + ct * 16 + lrow];
        f32x4 c = {iv, iv, iv, iv};
#pragma unroll
        for (int rt = 0; rt < 4; ++rt) acc[rt][ct] = c;
    }
    __syncthreads();

    const h16x8* W1h = (const h16x8*)W1hi;
    const h16x8* W1l = (const h16x8*)W1lo;
    for (int kt = 0; kt < 8; ++kt) {
        h16x8 a[4];
#pragma unroll
        for (int rt = 0; rt < 4; ++rt)
            a[rt] = *(const h16x8*)&sA1[(lrow + 16 * rt) * A2P + kt * 32 + q4 * 8];
#pragma unroll
        for (int ct = 0; ct < 4; ++ct) {
            h16x8 bh = W1h[(kt * 16 + w * 4 + ct) * 64 + lane];
            h16x8 bl = W1l[(kt * 16 + w * 4 + ct) * 64 + lane];
#pragma unroll
            for (int rt = 0; rt < 4; ++rt) {
                acc[rt][ct] = MFMA16(a[rt], bh, acc[rt][ct]);
                acc[rt][ct] = MFMA16(a[rt], bl, acc[rt][ct]);
            }
        }
    }

    __syncthreads();   // all sA1 reads done before aliased sA2 writes

#pragma unroll
    for (int rt = 0; rt < 4; ++rt)
#pragma unroll
        for (int ct = 0; ct < 4; ++ct)
#pragma unroll
            for (int j = 0; j < 4; ++j) {
                int hr = rt * 16 + q4 * 4 + j;
                int hc = w * 64 + ct * 16 + lrow;
                sA2[hr * A2P + hc] = f2h_bits(fmaxf(acc[rt][ct][j], 0.0f));
            }
    __syncthreads();

    // ---- GEMM2: [64x256] @ [256x128] -> acc2[4][2] ----
    f32x4 acc2[4][2];
#pragma unroll
    for (int ct = 0; ct < 2; ++ct) {
        float iv = b2[w * 32 + ct * 16 + lrow];
        f32x4 c = {iv, iv, iv, iv};
#pragma unroll
        for (int rt = 0; rt < 4; ++rt) acc2[rt][ct] = c;
    }
    const h16x8* W2h = (const h16x8*)W2hi;
    const h16x8* W2l = (const h16x8*)W2lo;
    for (int kt = 0; kt < 8; ++kt) {
        h16x8 a[4];
#pragma unroll
        for (int rt = 0; rt < 4; ++rt)
            a[rt] = *(const h16x8*)&sA2[(lrow + 16 * rt) * A2P + kt * 32 + q4 * 8];
#pragma unroll
        for (int ct = 0; ct < 2; ++ct) {
            h16x8 bh = W2h[(kt * 8 + w * 2 + ct) * 64 + lane];
            h16x8 bl = W2l[(kt * 8 + w * 2 + ct) * 64 + lane];
#pragma unroll
            for (int rt = 0; rt < 4; ++rt) {
                acc2[rt][ct] = MFMA16(a[rt], bh, acc2[rt][ct]);
                acc2[rt][ct] = MFMA16(a[rt], bl, acc2[rt][ct]);
            }
        }
    }

    // ---- epilogue: acc2 -> LDS out-stage (f16) -> coalesced 16B global stores ----
    __syncthreads();
#pragma unroll
    for (int rt = 0; rt < 4; ++rt)
#pragma unroll
        for (int j = 0; j < 4; ++j) {
            int rr = rt * 16 + q4 * 4 + j;
#pragma unroll
            for (int ct = 0; ct < 2; ++ct)
                sOut[rr * OP + w * 32 + ct * 16 + lrow] = f2h_bits(acc2[rt][ct][j]);
        }
    __syncthreads();
    if (vrow) {
        unsigned short* nr = node_out + (size_t)n * 256;
#pragma unroll
        for (int j = 0; j < 4; ++j)
            *(uint4*)(nr + t4 * 32 + j * 8) = *(const uint4*)&sOut[row * OP + t4 * 32 + j * 8];
    }
}

// ---------------- sigmoid(h @ w + b), f16 input rows (stride 256 halfs) ----------
__global__ void score_kernel(const unsigned short* __restrict__ hmat,
                             const float* __restrict__ w,
                             const float* __restrict__ b, float* __restrict__ out) {
    int wid = threadIdx.x >> 6;        // 4 waves per block, one row each
    int lane = threadIdx.x & 63;
    int row = blockIdx.x * 4 + wid;
    unsigned v = *(const unsigned*)(hmat + (size_t)row * 256 + lane * 2);
    float2 wv = *(const float2*)(w + lane * 2);
    float s = h2f((unsigned short)(v & 0xffff)) * wv.x +
              h2f((unsigned short)(v >> 16)) * wv.y;
#pragma unroll
    for (int off = 32; off; off >>= 1) s += __shfl_down(s, off);
    if (lane == 0) out[row] = 1.0f / (1.0f + expf(-(s + b[0])));
}

extern "C" void kernel_launch(void* const* d_in, const int* in_sizes, int n_in,
                              void* d_out, int out_size, void* d_ws, size_t ws_size,
                              hipStream_t stream) {
    float* node_h = (float*)d_in[0];            // mutated in place (restored each launch)
    float* edge_h = (float*)d_in[1];            // mutated in place
    const float* qe   = (const float*)d_in[2];
    const int*   eidx = (const int*)d_in[3];
    // d_in[4] edge_type: unused
    const float* qW  = (const float*)d_in[5];
    const float* qb  = (const float*)d_in[6];
    const float* eW1 = (const float*)d_in[7];
    const float* eb1 = (const float*)d_in[8];
    const float* eW2 = (const float*)d_in[9];
    const float* eb2 = (const float*)d_in[10];
    const float* nW1 = (const float*)d_in[11];
    const float* nb1 = (const float*)d_in[12];
    const float* nW2 = (const float*)d_in[13];
    const float* nb2 = (const float*)d_in[14];
    const float* esW = (const float*)d_in[15];
    const float* esb = (const float*)d_in[16];
    const float* nsW = (const float*)d_in[17];
    const float* nsb = (const float*)d_in[18];

    // f16 activation views: row n at half-offset n*256 (first 256B of the 512B slot)
    unsigned short* nh16 = (unsigned short*)node_h;
    unsigned short* eh16 = (unsigned short*)edge_h;

    float* ws  = (float*)d_ws;
    float* q   = ws;            // 128 floats
    float* qc  = ws + 256;      // 3*256 floats
    int* cnt     = (int*)(ws + 1024);   // NN
    int* cursor  = cnt + NN;            // NN
    int* offsets = cursor + NN;         // NN+1
    int* inc     = offsets + NN + 1;    // 2*NE   (total ~6.3 MB)

    // f16 weight packs (hi+lo planes) live in d_out (dead until score writes).
    unsigned short* packs = (unsigned short*)d_out;
    const size_t pe1 = (size_t)NL * 384 * 256;
    const size_t pe2 = (size_t)NL * 256 * 128;
    const size_t pn1 = (size_t)NL * 256 * 256;
    const size_t pn2 = (size_t)NL * 256 * 128;
    unsigned short* eW1p = packs;
    unsigned short* eW2p = eW1p + 2 * pe1;
    unsigned short* nW1p = eW2p + 2 * pe2;
    unsigned short* nW2p = nW1p + 2 * pn1;

    q_kernel<<<1, DD, 0, stream>>>(qe, qW, qb, q);
    qc_kernel<<<NL, HH, 0, stream>>>(q, eW1, eb1, qc);
    pack_kernel<<<dim3(12 * 16, NL), 64, 0, stream>>>(eW1, eW1p, 384, 256, 4 * DD * HH, pe1);
    pack_kernel<<<dim3(8 * 8, NL), 64, 0, stream>>>(eW2, eW2p, 256, 128, HH * DD, pe2);
    pack_kernel<<<dim3(8 * 16, NL), 64, 0, stream>>>(nW1, nW1p, 256, 256, 2 * DD * HH, pn1);
    pack_kernel<<<dim3(8 * 8, NL), 64, 0, stream>>>(nW2, nW2p, 256, 128, HH * DD, pn2);

    // ---- CSR incidence build (once; edge_index is layer-invariant) ----
    hipMemsetAsync(cnt, 0, NN * sizeof(int), stream);
    deg_kernel<<<(2 * NE + 255) / 256, 256, 0, stream>>>(eidx, cnt);
    scan_kernel<<<1, SCAN_T, 0, stream>>>(cnt, offsets, cursor);
    fill_kernel<<<(2 * NE + 255) / 256, 256, 0, stream>>>(eidx, cursor, inc);

    for (int l = 0; l < NL; ++l) {
        if (l == 0) {
            edge_kernel<false><<<NE / TM, 256, 0, stream>>>(
                (const void*)node_h, (const void*)edge_h, eh16, eidx,
                eW1p + (size_t)l * 384 * 256, eW1p + pe1 + (size_t)l * 384 * 256,
                qc + l * HH,
                eW2p + (size_t)l * 256 * 128, eW2p + pe2 + (size_t)l * 256 * 128,
                eb2 + l * DD);
            node_kernel<false><<<(NN + TM - 1) / TM, 256, 0, stream>>>(
                (const void*)node_h, nh16, eh16, offsets, inc,
                nW1p + (size_t)l * 256 * 256, nW1p + pn1 + (size_t)l * 256 * 256,
                nb1 + l * HH,
                nW2p + (size_t)l * 256 * 128, nW2p + pn2 + (size_t)l * 256 * 128,
                nb2 + l * DD);
        } else {
            edge_kernel<true><<<NE / TM, 256, 0, stream>>>(
                (const void*)nh16, (const void*)eh16, eh16, eidx,
                eW1p + (size_t)l * 384 * 256, eW1p + pe1 + (size_t)l * 384 * 256,
                qc + l * HH,
                eW2p + (size_t)l * 256 * 128, eW2p + pe2 + (size_t)l * 256 * 128,
                eb2 + l * DD);
            node_kernel<true><<<(NN + TM - 1) / TM, 256, 0, stream>>>(
                (const void*)nh16, nh16, eh16, offsets, inc,
                nW1p + (size_t)l * 256 * 256, nW1p + pn1 + (size_t)l * 256 * 256,
                nb1 + l * HH,
                nW2p + (size_t)l * 256 * 128, nW2p + pn2 + (size_t)l * 256 * 128,
                nb2 + l * DD);
        }
    }

    score_kernel<<<NN / 4, 256, 0, stream>>>(nh16, nsW, nsb, (float*)d_out);
    score_kernel<<<NE / 4, 256, 0, stream>>>(eh16, esW, esb, (float*)d_out + NN);
}